// Round 1
// baseline (326.001 us; speedup 1.0000x reference)
//
#include <hip/hip_runtime.h>
#include <stdint.h>

// Causal self-attention: x[8,2048,256] fp32, W_attn[768,256], W_proj[256,256]
// Pipeline: cvt->bf16, QKV GEMM (v stored transposed), flash attn, proj GEMM.
// All matmuls via mfma_f32_16x16x32_bf16, fp32 accum.

#define BB 8
#define SS 2048
#define CC 256
#define HH 4
#define DD 64

typedef __attribute__((ext_vector_type(8))) __bf16 bf16x8;
typedef __attribute__((ext_vector_type(4))) __bf16 bf16x4;
typedef __attribute__((ext_vector_type(4))) float f32x4;

// ---------------- fp32 -> bf16 convert (vectorized, RNE via compiler) -------
__global__ __launch_bounds__(256) void cvt_kernel(const float* __restrict__ in,
                                                  __bf16* __restrict__ out, int n4) {
  int i = blockIdx.x * blockDim.x + threadIdx.x;
  if (i >= n4) return;
  float4 v = ((const float4*)in)[i];
  bf16x4 o = { (__bf16)v.x, (__bf16)v.y, (__bf16)v.z, (__bf16)v.w };
  *(bf16x4*)(out + 4 * i) = o;
}

// ---------------- QKV GEMM: qkv = x @ W_attn^T ------------------------------
// wave computes 16 rows x 64 cols. q,k -> [BH][S][D]; v -> [BH][D][S] (transposed)
__global__ __launch_bounds__(256) void qkv_gemm(const __bf16* __restrict__ xb,
                                                const __bf16* __restrict__ wb,
                                                __bf16* __restrict__ qb,
                                                __bf16* __restrict__ kb,
                                                __bf16* __restrict__ vtb) {
  const int lane = threadIdx.x & 63;
  const int ln = lane & 15, kg = lane >> 4;
  const int gw = blockIdx.x * 4 + (threadIdx.x >> 6);
  const int mtile = gw / 12;
  const int otile = gw % 12;
  const int row = mtile * 16 + ln;

  f32x4 acc[4] = {};
  const __bf16* xrow = xb + row * CC + kg * 8;
  for (int c0 = 0; c0 < CC; c0 += 32) {
    bf16x8 a = *(const bf16x8*)(xrow + c0);
#pragma unroll
    for (int t = 0; t < 4; ++t) {
      int o = otile * 64 + t * 16 + ln;
      bf16x8 w = *(const bf16x8*)(wb + o * CC + c0 + kg * 8);
      acc[t] = __builtin_amdgcn_mfma_f32_16x16x32_bf16(a, w, acc[t], 0, 0, 0);
    }
  }
#pragma unroll
  for (int t = 0; t < 4; ++t) {
    int o = otile * 64 + t * 16 + ln;
    int sel = o >> 8;         // 0=q 1=k 2=v
    int oo = o & 255;
    int h = oo >> 6, d = oo & 63;
#pragma unroll
    for (int r = 0; r < 4; ++r) {
      int rout = mtile * 16 + kg * 4 + r;
      int b = rout >> 11, s = rout & 2047;
      __bf16 v = (__bf16)acc[t][r];
      if (sel == 0)      qb[((b * HH + h) * SS + s) * DD + d] = v;
      else if (sel == 1) kb[((b * HH + h) * SS + s) * DD + d] = v;
      else               vtb[((b * HH + h) * DD + d) * SS + s] = v;
    }
  }
}

// ---------------- Flash attention (causal, online softmax) ------------------
// grid (32 qtiles, 32 bh), 4 waves/block, each wave: 16 q-rows, k-tiles of 32.
__global__ __launch_bounds__(256) void attn_kernel(const __bf16* __restrict__ qb,
                                                   const __bf16* __restrict__ kb,
                                                   const __bf16* __restrict__ vtb,
                                                   __bf16* __restrict__ yb) {
  __shared__ __bf16 plds[4][16][40];   // +8 pad: 16B-aligned rows, 2-way banks
  const int lane = threadIdx.x & 63;
  const int ln = lane & 15, kg = lane >> 4;
  const int w = threadIdx.x >> 6;
  const int bh = blockIdx.y;
  const int q0 = blockIdx.x * 64 + w * 16;

  const __bf16* Q = qb + bh * SS * DD;
  const __bf16* K = kb + bh * SS * DD;
  const __bf16* VT = vtb + bh * DD * SS;

  bf16x8 qf0 = *(const bf16x8*)(Q + (q0 + ln) * DD + kg * 8);
  bf16x8 qf1 = *(const bf16x8*)(Q + (q0 + ln) * DD + 32 + kg * 8);

  f32x4 acc[4] = {};
  float mrun[4], lrun[4];
#pragma unroll
  for (int r = 0; r < 4; ++r) { mrun[r] = -1e30f; lrun[r] = 0.f; }

  const float cm = 0.18033688011112042f;  // (1/sqrt(64)) * log2(e)
  const int nkt = (q0 + 47) >> 5;
  for (int kt = 0; kt < nkt; ++kt) {
    const int kbase = kt * 32;
    bf16x8 k00 = *(const bf16x8*)(K + (kbase + ln) * DD + kg * 8);
    bf16x8 k01 = *(const bf16x8*)(K + (kbase + ln) * DD + 32 + kg * 8);
    bf16x8 k10 = *(const bf16x8*)(K + (kbase + 16 + ln) * DD + kg * 8);
    bf16x8 k11 = *(const bf16x8*)(K + (kbase + 16 + ln) * DD + 32 + kg * 8);
    f32x4 s0 = {}, s1 = {};
    s0 = __builtin_amdgcn_mfma_f32_16x16x32_bf16(qf0, k00, s0, 0, 0, 0);
    s0 = __builtin_amdgcn_mfma_f32_16x16x32_bf16(qf1, k01, s0, 0, 0, 0);
    s1 = __builtin_amdgcn_mfma_f32_16x16x32_bf16(qf0, k10, s1, 0, 0, 0);
    s1 = __builtin_amdgcn_mfma_f32_16x16x32_bf16(qf1, k11, s1, 0, 0, 0);

    float p0[4], p1[4], al[4];
#pragma unroll
    for (int r = 0; r < 4; ++r) {
      int qi = q0 + kg * 4 + r;
      int k0i = kbase + ln;
      float v0 = (k0i <= qi) ? s0[r] * cm : -1e30f;
      float v1 = (k0i + 16 <= qi) ? s1[r] * cm : -1e30f;
      float t = fmaxf(v0, v1);
      t = fmaxf(t, __shfl_xor(t, 1));
      t = fmaxf(t, __shfl_xor(t, 2));
      t = fmaxf(t, __shfl_xor(t, 4));
      t = fmaxf(t, __shfl_xor(t, 8));
      float mnew = fmaxf(mrun[r], t);
      float a = __builtin_amdgcn_exp2f(mrun[r] - mnew);
      mrun[r] = mnew;
      al[r] = a;
      p0[r] = __builtin_amdgcn_exp2f(v0 - mnew);
      p1[r] = __builtin_amdgcn_exp2f(v1 - mnew);
      float sum = p0[r] + p1[r];
      sum += __shfl_xor(sum, 1);
      sum += __shfl_xor(sum, 2);
      sum += __shfl_xor(sum, 4);
      sum += __shfl_xor(sum, 8);
      lrun[r] = lrun[r] * a + sum;
    }
    // transpose P via LDS (D-layout -> A-fragment layout)
#pragma unroll
    for (int r = 0; r < 4; ++r) {
      plds[w][kg * 4 + r][ln] = (__bf16)p0[r];
      plds[w][kg * 4 + r][ln + 16] = (__bf16)p1[r];
    }
    bf16x8 pf = *(const bf16x8*)(&plds[w][ln][kg * 8]);
#pragma unroll
    for (int t = 0; t < 4; ++t) {
      bf16x8 vf = *(const bf16x8*)(VT + (t * 16 + ln) * SS + kbase + kg * 8);
#pragma unroll
      for (int r = 0; r < 4; ++r) acc[t][r] *= al[r];
      acc[t] = __builtin_amdgcn_mfma_f32_16x16x32_bf16(pf, vf, acc[t], 0, 0, 0);
    }
  }
#pragma unroll
  for (int r = 0; r < 4; ++r) {
    float inv = 1.0f / lrun[r];
    int qi = q0 + kg * 4 + r;
#pragma unroll
    for (int t = 0; t < 4; ++t)
      yb[bh * SS * DD + qi * DD + t * 16 + ln] = (__bf16)(acc[t][r] * inv);
  }
}

// ---------------- Proj GEMM: out = y @ W_proj^T (fp32 out) ------------------
__global__ __launch_bounds__(256) void proj_gemm(const __bf16* __restrict__ yb,
                                                 const __bf16* __restrict__ wpb,
                                                 float* __restrict__ out) {
  const int lane = threadIdx.x & 63;
  const int ln = lane & 15, kg = lane >> 4;
  const int gw = blockIdx.x * 4 + (threadIdx.x >> 6);
  const int mtile = gw >> 2;
  const int otile = gw & 3;
  const int row = mtile * 16 + ln;
  const int b = row >> 11, s = row & 2047;

  f32x4 acc[4] = {};
  for (int kk = 0; kk < 8; ++kk) {
    int c = kk * 32 + kg * 8;
    int h = c >> 6, d = c & 63;
    bf16x8 a = *(const bf16x8*)(yb + ((b * HH + h) * SS + s) * DD + d);
#pragma unroll
    for (int t = 0; t < 4; ++t) {
      int o = otile * 64 + t * 16 + ln;
      bf16x8 w = *(const bf16x8*)(wpb + o * CC + kk * 32 + kg * 8);
      acc[t] = __builtin_amdgcn_mfma_f32_16x16x32_bf16(a, w, acc[t], 0, 0, 0);
    }
  }
#pragma unroll
  for (int t = 0; t < 4; ++t) {
    int o = otile * 64 + t * 16 + ln;
#pragma unroll
    for (int r = 0; r < 4; ++r) {
      int rout = mtile * 16 + kg * 4 + r;
      out[rout * 256 + o] = acc[t][r];
    }
  }
}

extern "C" void kernel_launch(void* const* d_in, const int* in_sizes, int n_in,
                              void* d_out, int out_size, void* d_ws, size_t ws_size,
                              hipStream_t stream) {
  const float* x = (const float*)d_in[0];
  const float* Wa = (const float*)d_in[1];
  const float* Wp = (const float*)d_in[2];

  char* ws = (char*)d_ws;
  __bf16* xb  = (__bf16*)(ws);                    // 8 MiB  [B*S][C]
  __bf16* qb  = (__bf16*)(ws + 8388608);          // 8 MiB  [BH][S][D]
  __bf16* kb  = (__bf16*)(ws + 16777216);         // 8 MiB  [BH][S][D]
  __bf16* vtb = (__bf16*)(ws + 25165824);         // 8 MiB  [BH][D][S]
  __bf16* yb  = (__bf16*)(ws + 33554432);         // 8 MiB  [BH][S][D]
  __bf16* wab = (__bf16*)(ws + 41943040);         // 384 KiB [768][256]
  __bf16* wpb = (__bf16*)(ws + 42336256);         // 128 KiB [256][256]

  cvt_kernel<<<(4194304 / 4 + 255) / 256, 256, 0, stream>>>(x, xb, 4194304 / 4);
  cvt_kernel<<<(196608 / 4 + 255) / 256, 256, 0, stream>>>(Wa, wab, 196608 / 4);
  cvt_kernel<<<(65536 / 4 + 255) / 256, 256, 0, stream>>>(Wp, wpb, 65536 / 4);

  qkv_gemm<<<3072, 256, 0, stream>>>(xb, wab, qb, kb, vtb);
  attn_kernel<<<dim3(32, 32), 256, 0, stream>>>(qb, kb, vtb, yb);
  proj_gemm<<<1024, 256, 0, stream>>>(yb, wpb, (float*)d_out);
}

// Round 2
// 218.780 us; speedup vs baseline: 1.4901x; 1.4901x over previous
//
#include <hip/hip_runtime.h>
#include <stdint.h>

// Causal self-attention: x[8,2048,256] fp32, W_attn[768,256], W_proj[256,256]
// cvt->bf16, QKV GEMM (v transposed), flash attn (swapped-QK, lane-local softmax),
// proj GEMM. All matmuls mfma_f32_16x16x32_bf16, fp32 accum.

#define BB 8
#define SS 2048
#define CC 256
#define HH 4
#define DD 64

typedef __attribute__((ext_vector_type(8))) __bf16 bf16x8;
typedef __attribute__((ext_vector_type(4))) __bf16 bf16x4;
typedef __attribute__((ext_vector_type(4))) float f32x4;

// ---------------- fp32 -> bf16 convert ----------------
__global__ __launch_bounds__(256) void cvt_kernel(const float* __restrict__ in,
                                                  __bf16* __restrict__ out, int n4) {
  int i = blockIdx.x * blockDim.x + threadIdx.x;
  if (i >= n4) return;
  float4 v = ((const float4*)in)[i];
  bf16x4 o = { (__bf16)v.x, (__bf16)v.y, (__bf16)v.z, (__bf16)v.w };
  *(bf16x4*)(out + 4 * i) = o;
}

// ---------------- QKV GEMM: qkv = x @ W_attn^T ----------------
// Block: 4 waves share ONE otile (W reuse via L1), distinct mtiles.
__global__ __launch_bounds__(256) void qkv_gemm(const __bf16* __restrict__ xb,
                                                const __bf16* __restrict__ wb,
                                                __bf16* __restrict__ qb,
                                                __bf16* __restrict__ kb,
                                                __bf16* __restrict__ vtb) {
  const int lane = threadIdx.x & 63;
  const int ln = lane & 15, kg = lane >> 4;
  const int w = threadIdx.x >> 6;
  const int otile = blockIdx.x % 12;
  const int mtile = (blockIdx.x / 12) * 4 + w;
  const int row = mtile * 16 + ln;

  f32x4 acc[4] = {};
  const __bf16* xrow = xb + row * CC + kg * 8;
  for (int c0 = 0; c0 < CC; c0 += 32) {
    bf16x8 a = *(const bf16x8*)(xrow + c0);
#pragma unroll
    for (int t = 0; t < 4; ++t) {
      int o = otile * 64 + t * 16 + ln;
      bf16x8 wv = *(const bf16x8*)(wb + o * CC + c0 + kg * 8);
      acc[t] = __builtin_amdgcn_mfma_f32_16x16x32_bf16(a, wv, acc[t], 0, 0, 0);
    }
  }
#pragma unroll
  for (int t = 0; t < 4; ++t) {
    int o = otile * 64 + t * 16 + ln;
    int sel = o >> 8;         // 0=q 1=k 2=v
    int oo = o & 255;
    int h = oo >> 6, d = oo & 63;
#pragma unroll
    for (int r = 0; r < 4; ++r) {
      int rout = mtile * 16 + kg * 4 + r;
      int b = rout >> 11, s = rout & 2047;
      __bf16 v = (__bf16)acc[t][r];
      if (sel == 0)      qb[((b * HH + h) * SS + s) * DD + d] = v;
      else if (sel == 1) kb[((b * HH + h) * SS + s) * DD + d] = v;
      else               vtb[((b * HH + h) * DD + d) * SS + s] = v;
    }
  }
}

// ---------------- Flash attention (swapped QK^T, lane-local softmax) --------
// 1024 blocks x 4 waves. Wave handles 16 q-rows (one chunk). Lane owns q=q0+ln;
// scores live in regs as s[key=kg*4+r][q=ln]. XCD swizzle: bh % 8 pinned per XCD.
__global__ __launch_bounds__(256) void attn_kernel(const __bf16* __restrict__ qb,
                                                   const __bf16* __restrict__ kb,
                                                   const __bf16* __restrict__ vtb,
                                                   __bf16* __restrict__ yb) {
  __shared__ __bf16 plds[4][16][56];   // row stride 112B: 16B-aligned, 2-way banks
  const int lane = threadIdx.x & 63;
  const int ln = lane & 15, kg = lane >> 4;
  const int w = threadIdx.x >> 6;
  const int gid = blockIdx.x;
  const int xs = gid & 7, j = gid >> 3;
  const int bh = xs + ((j >> 5) << 3);     // 4 bh per XCD slot -> 2MB KV in L2
  const int cg = j & 31;
  const int i = cg * 4 + w;                // 0..127
  const int c = (i & 1) ? (127 - (i >> 1)) : (i >> 1);   // fold: balance blocks
  const int q0 = c * 16;
  const int q = q0 + ln;

  const __bf16* Q = qb + bh * SS * DD;
  const __bf16* K = kb + bh * SS * DD;
  const __bf16* VT = vtb + bh * DD * SS;

  bf16x8 qf0 = *(const bf16x8*)(Q + q * DD + kg * 8);
  bf16x8 qf1 = *(const bf16x8*)(Q + q * DD + 32 + kg * 8);

  f32x4 acc[4] = {};
  float mrun = -1e30f, lrun = 0.0f;
  const float cm = 0.18033688011112042f;  // (1/sqrt(64)) * log2(e)
  const int nkt = (q0 + 47) >> 5;

  // preload K tile 0 (A-operand: rows = keys)
  const __bf16* Kr = K + ln * DD + kg * 8;
  bf16x8 ka0 = *(const bf16x8*)(Kr);
  bf16x8 ka1 = *(const bf16x8*)(Kr + 32);
  bf16x8 kc0 = *(const bf16x8*)(Kr + 16 * DD);
  bf16x8 kc1 = *(const bf16x8*)(Kr + 16 * DD + 32);

  for (int kt = 0; kt < nkt; ++kt) {
    const int kbase = kt * 32;
    // prefetch next K tile (register double-buffer)
    const int pb = (kt + 1 < nkt) ? (kbase + 32) : kbase;
    const __bf16* Kn = K + (pb + ln) * DD + kg * 8;
    bf16x8 na0 = *(const bf16x8*)(Kn);
    bf16x8 na1 = *(const bf16x8*)(Kn + 32);
    bf16x8 nc0 = *(const bf16x8*)(Kn + 16 * DD);
    bf16x8 nc1 = *(const bf16x8*)(Kn + 16 * DD + 32);
    // V loads for current tile (independent; land during softmax)
    const __bf16* Vp = VT + ln * SS + kbase + kg * 8;
    bf16x8 vt0 = *(const bf16x8*)(Vp);
    bf16x8 vt1 = *(const bf16x8*)(Vp + 16 * SS);
    bf16x8 vt2 = *(const bf16x8*)(Vp + 32 * SS);
    bf16x8 vt3 = *(const bf16x8*)(Vp + 48 * SS);

    // swapped QK: s[key-row][q-col]; lane holds keys kg*4+r (+16) for q=q0+ln
    f32x4 s0 = {}, s1 = {};
    s0 = __builtin_amdgcn_mfma_f32_16x16x32_bf16(ka0, qf0, s0, 0, 0, 0);
    s0 = __builtin_amdgcn_mfma_f32_16x16x32_bf16(ka1, qf1, s0, 0, 0, 0);
    s1 = __builtin_amdgcn_mfma_f32_16x16x32_bf16(kc0, qf0, s1, 0, 0, 0);
    s1 = __builtin_amdgcn_mfma_f32_16x16x32_bf16(kc1, qf1, s1, 0, 0, 0);

    float p0[4], p1[4];
    float tmax = -1e30f;
#pragma unroll
    for (int r = 0; r < 4; ++r) {
      int key0 = kbase + kg * 4 + r;
      p0[r] = (key0 <= q) ? s0[r] * cm : -1e30f;
      p1[r] = (key0 + 16 <= q) ? s1[r] * cm : -1e30f;
      tmax = fmaxf(tmax, fmaxf(p0[r], p1[r]));
    }
    tmax = fmaxf(tmax, __shfl_xor(tmax, 16));
    tmax = fmaxf(tmax, __shfl_xor(tmax, 32));
    float mnew = fmaxf(mrun, tmax);
    float al = __builtin_amdgcn_exp2f(mrun - mnew);
    mrun = mnew;
    float sum = 0.0f;
#pragma unroll
    for (int r = 0; r < 4; ++r) {
      p0[r] = __builtin_amdgcn_exp2f(p0[r] - mnew);
      p1[r] = __builtin_amdgcn_exp2f(p1[r] - mnew);
      sum += p0[r] + p1[r];
    }
    sum += __shfl_xor(sum, 16);
    sum += __shfl_xor(sum, 32);
    lrun = lrun * al + sum;

    // repack P: [q=ln][key] via tiny LDS roundtrip -> B-fragment
    bf16x4 pb0 = { (__bf16)p0[0], (__bf16)p0[1], (__bf16)p0[2], (__bf16)p0[3] };
    bf16x4 pb1 = { (__bf16)p1[0], (__bf16)p1[1], (__bf16)p1[2], (__bf16)p1[3] };
    *(bf16x4*)(&plds[w][ln][kg * 4]) = pb0;
    *(bf16x4*)(&plds[w][ln][16 + kg * 4]) = pb1;
    bf16x8 pf = *(const bf16x8*)(&plds[w][ln][kg * 8]);

#pragma unroll
    for (int t = 0; t < 4; ++t)
#pragma unroll
      for (int r = 0; r < 4; ++r) acc[t][r] *= al;
    acc[0] = __builtin_amdgcn_mfma_f32_16x16x32_bf16(vt0, pf, acc[0], 0, 0, 0);
    acc[1] = __builtin_amdgcn_mfma_f32_16x16x32_bf16(vt1, pf, acc[1], 0, 0, 0);
    acc[2] = __builtin_amdgcn_mfma_f32_16x16x32_bf16(vt2, pf, acc[2], 0, 0, 0);
    acc[3] = __builtin_amdgcn_mfma_f32_16x16x32_bf16(vt3, pf, acc[3], 0, 0, 0);

    ka0 = na0; ka1 = na1; kc0 = nc0; kc1 = nc1;
  }

  // acc[t][r] = y[q][d = t*16 + kg*4 + r]; write y in [B,S,C] layout
  const int b = bh >> 2, h = bh & 3;
  __bf16* yrow = yb + (b * SS + q) * CC + h * DD;
  float inv = 1.0f / lrun;
#pragma unroll
  for (int t = 0; t < 4; ++t) {
    bf16x4 o = { (__bf16)(acc[t][0] * inv), (__bf16)(acc[t][1] * inv),
                 (__bf16)(acc[t][2] * inv), (__bf16)(acc[t][3] * inv) };
    *(bf16x4*)(yrow + t * 16 + kg * 4) = o;
  }
}

// ---------------- Proj GEMM: out = y @ W_proj^T (fp32 out) ------------------
__global__ __launch_bounds__(256) void proj_gemm(const __bf16* __restrict__ yb,
                                                 const __bf16* __restrict__ wpb,
                                                 float* __restrict__ out) {
  const int lane = threadIdx.x & 63;
  const int ln = lane & 15, kg = lane >> 4;
  const int w = threadIdx.x >> 6;
  const int otile = blockIdx.x & 3;
  const int mtile = (blockIdx.x >> 2) * 4 + w;
  const int row = mtile * 16 + ln;

  f32x4 acc[4] = {};
  const __bf16* yrow = yb + row * CC + kg * 8;
  for (int c0 = 0; c0 < CC; c0 += 32) {
    bf16x8 a = *(const bf16x8*)(yrow + c0);
#pragma unroll
    for (int t = 0; t < 4; ++t) {
      int o = otile * 64 + t * 16 + ln;
      bf16x8 wv = *(const bf16x8*)(wpb + o * CC + c0 + kg * 8);
      acc[t] = __builtin_amdgcn_mfma_f32_16x16x32_bf16(a, wv, acc[t], 0, 0, 0);
    }
  }
#pragma unroll
  for (int t = 0; t < 4; ++t) {
    int o = otile * 64 + t * 16 + ln;
#pragma unroll
    for (int r = 0; r < 4; ++r) {
      int rout = mtile * 16 + kg * 4 + r;
      out[rout * 256 + o] = acc[t][r];
    }
  }
}

extern "C" void kernel_launch(void* const* d_in, const int* in_sizes, int n_in,
                              void* d_out, int out_size, void* d_ws, size_t ws_size,
                              hipStream_t stream) {
  const float* x = (const float*)d_in[0];
  const float* Wa = (const float*)d_in[1];
  const float* Wp = (const float*)d_in[2];

  char* ws = (char*)d_ws;
  __bf16* xb  = (__bf16*)(ws);                    // 8 MiB  [B*S][C]
  __bf16* qb  = (__bf16*)(ws + 8388608);          // 8 MiB  [BH][S][D]
  __bf16* kb  = (__bf16*)(ws + 16777216);         // 8 MiB  [BH][S][D]
  __bf16* vtb = (__bf16*)(ws + 25165824);         // 8 MiB  [BH][D][S]
  __bf16* yb  = (__bf16*)(ws + 33554432);         // 8 MiB  [B,S,C]
  __bf16* wab = (__bf16*)(ws + 41943040);         // 384 KiB [768][256]
  __bf16* wpb = (__bf16*)(ws + 42336256);         // 128 KiB [256][256]

  cvt_kernel<<<(4194304 / 4 + 255) / 256, 256, 0, stream>>>(x, xb, 4194304 / 4);
  cvt_kernel<<<(196608 / 4 + 255) / 256, 256, 0, stream>>>(Wa, wab, 196608 / 4);
  cvt_kernel<<<(65536 / 4 + 255) / 256, 256, 0, stream>>>(Wp, wpb, 65536 / 4);

  qkv_gemm<<<3072, 256, 0, stream>>>(xb, wab, qb, kb, vtb);
  attn_kernel<<<1024, 256, 0, stream>>>(qb, kb, vtb, yb);
  proj_gemm<<<1024, 256, 0, stream>>>(yb, wpb, (float*)d_out);
}

// Round 3
// 199.404 us; speedup vs baseline: 1.6349x; 1.0972x over previous
//
#include <hip/hip_runtime.h>
#include <stdint.h>

// Causal self-attention: x[8,2048,256] fp32, W_attn[768,256], W_proj[256,256]
// cvt->bf16, QKV GEMM (v transposed), split-K flash attn (4 waves/chunk,
// LDS combine), proj GEMM. All matmuls mfma_f32_16x16x32_bf16, fp32 accum.

#define BB 8
#define SS 2048
#define CC 256
#define HH 4
#define DD 64

typedef __attribute__((ext_vector_type(8))) __bf16 bf16x8;
typedef __attribute__((ext_vector_type(4))) __bf16 bf16x4;
typedef __attribute__((ext_vector_type(4))) float f32x4;

// ---------------- fp32 -> bf16 convert ----------------
__global__ __launch_bounds__(256) void cvt_kernel(const float* __restrict__ in,
                                                  __bf16* __restrict__ out, int n4) {
  int i = blockIdx.x * blockDim.x + threadIdx.x;
  if (i >= n4) return;
  float4 v = ((const float4*)in)[i];
  bf16x4 o = { (__bf16)v.x, (__bf16)v.y, (__bf16)v.z, (__bf16)v.w };
  *(bf16x4*)(out + 4 * i) = o;
}

// ---------------- QKV GEMM: qkv = x @ W_attn^T ----------------
// Wave: 64 rows x 64 cols (16 MFMA per 32-K step). Block: 4 waves share otile.
__global__ __launch_bounds__(256) void qkv_gemm(const __bf16* __restrict__ xb,
                                                const __bf16* __restrict__ wb,
                                                __bf16* __restrict__ qb,
                                                __bf16* __restrict__ kb,
                                                __bf16* __restrict__ vtb) {
  const int lane = threadIdx.x & 63;
  const int ln = lane & 15, kg = lane >> 4;
  const int w = threadIdx.x >> 6;
  const int otile = blockIdx.x % 12;
  const int r0 = (blockIdx.x / 12) * 256 + w * 64;
  const int o0 = otile * 64;

  f32x4 acc[4][4] = {};
  for (int c0 = 0; c0 < CC; c0 += 32) {
    bf16x8 a[4], wv[4];
#pragma unroll
    for (int i = 0; i < 4; ++i)
      a[i] = *(const bf16x8*)(xb + (r0 + i * 16 + ln) * CC + c0 + kg * 8);
#pragma unroll
    for (int t = 0; t < 4; ++t)
      wv[t] = *(const bf16x8*)(wb + (o0 + t * 16 + ln) * CC + c0 + kg * 8);
#pragma unroll
    for (int i = 0; i < 4; ++i)
#pragma unroll
      for (int t = 0; t < 4; ++t)
        acc[i][t] = __builtin_amdgcn_mfma_f32_16x16x32_bf16(a[i], wv[t], acc[i][t], 0, 0, 0);
  }
#pragma unroll
  for (int i = 0; i < 4; ++i)
#pragma unroll
    for (int t = 0; t < 4; ++t) {
      int o = o0 + t * 16 + ln;
      int sel = o >> 8;         // 0=q 1=k 2=v  (uniform per block)
      int oo = o & 255;
      int h = oo >> 6, d = oo & 63;
#pragma unroll
      for (int r = 0; r < 4; ++r) {
        int rout = r0 + i * 16 + kg * 4 + r;
        int b = rout >> 11, s = rout & 2047;
        __bf16 v = (__bf16)acc[i][t][r];
        if (sel == 0)      qb[((b * HH + h) * SS + s) * DD + d] = v;
        else if (sel == 1) kb[((b * HH + h) * SS + s) * DD + d] = v;
        else               vtb[((b * HH + h) * DD + d) * SS + s] = v;
      }
    }
}

// ---------------- Split-K flash attention ----------------
// 4096 blocks = 32 bh x 128 chunks. Block's 4 waves split the chunk's key
// range into contiguous quarters; online-softmax partials combined via LDS.
__global__ __launch_bounds__(256) void attn_kernel(const __bf16* __restrict__ qb,
                                                   const __bf16* __restrict__ kb,
                                                   const __bf16* __restrict__ vtb,
                                                   __bf16* __restrict__ yb) {
  __shared__ float smem[3840];   // 15360 B: plds (7168 B) then partials[3][64][20]
  const int lane = threadIdx.x & 63;
  const int ln = lane & 15, kg = lane >> 4;
  const int w = threadIdx.x >> 6;
  const int gid = blockIdx.x;
  const int xs = gid & 7, j = gid >> 3;
  const int bh = xs + ((j >> 7) << 3);     // 4 bh per XCD -> 2MB KV in L2
  const int c = 127 - (j & 127);           // longest chunks dispatched first
  const int q0 = c * 16;
  const int q = q0 + ln;

  const __bf16* Q = qb + bh * SS * DD;
  const __bf16* K = kb + bh * SS * DD;
  const __bf16* VT = vtb + bh * DD * SS;

  const int nkt = (q0 + 47) >> 5;          // 32-key tiles for this chunk
  const int seg = (nkt + 3) >> 2;
  const int kt0 = w * seg;
  const int kt1 = min(kt0 + seg, nkt);

  bf16x8 qf0 = *(const bf16x8*)(Q + q * DD + kg * 8);
  bf16x8 qf1 = *(const bf16x8*)(Q + q * DD + 32 + kg * 8);

  f32x4 acc[4] = {};
  float mrun = -1e30f, lrun = 0.0f;
  const float cm = 0.18033688011112042f;   // (1/sqrt(64)) * log2(e)

  // preload first K tile of this wave's segment (always in-bounds: kt0 <= 51)
  {
    const __bf16* Kr = K + (kt0 * 32 + ln) * DD + kg * 8;
    // fallthrough into loop-carried regs
  }
  const __bf16* Kr0 = K + (kt0 * 32 + ln) * DD + kg * 8;
  bf16x8 ka0 = *(const bf16x8*)(Kr0);
  bf16x8 ka1 = *(const bf16x8*)(Kr0 + 32);
  bf16x8 kc0 = *(const bf16x8*)(Kr0 + 16 * DD);
  bf16x8 kc1 = *(const bf16x8*)(Kr0 + 16 * DD + 32);

  __bf16* plds = (__bf16*)smem;            // [4][16][56]

  for (int kt = kt0; kt < kt1; ++kt) {
    const int kbase = kt * 32;
    // register double-buffer: prefetch next K tile
    const int pb = (kt + 1 < kt1) ? (kbase + 32) : kbase;
    const __bf16* Kn = K + (pb + ln) * DD + kg * 8;
    bf16x8 na0 = *(const bf16x8*)(Kn);
    bf16x8 na1 = *(const bf16x8*)(Kn + 32);
    bf16x8 nc0 = *(const bf16x8*)(Kn + 16 * DD);
    bf16x8 nc1 = *(const bf16x8*)(Kn + 16 * DD + 32);
    // V loads (independent; land during softmax)
    const __bf16* Vp = VT + ln * SS + kbase + kg * 8;
    bf16x8 vt0 = *(const bf16x8*)(Vp);
    bf16x8 vt1 = *(const bf16x8*)(Vp + 16 * SS);
    bf16x8 vt2 = *(const bf16x8*)(Vp + 32 * SS);
    bf16x8 vt3 = *(const bf16x8*)(Vp + 48 * SS);

    f32x4 s0 = {}, s1 = {};
    s0 = __builtin_amdgcn_mfma_f32_16x16x32_bf16(ka0, qf0, s0, 0, 0, 0);
    s0 = __builtin_amdgcn_mfma_f32_16x16x32_bf16(ka1, qf1, s0, 0, 0, 0);
    s1 = __builtin_amdgcn_mfma_f32_16x16x32_bf16(kc0, qf0, s1, 0, 0, 0);
    s1 = __builtin_amdgcn_mfma_f32_16x16x32_bf16(kc1, qf1, s1, 0, 0, 0);

    float p0[4], p1[4];
    float tmax = -1e30f;
#pragma unroll
    for (int r = 0; r < 4; ++r) {
      int key0 = kbase + kg * 4 + r;
      p0[r] = (key0 <= q) ? s0[r] * cm : -1e30f;
      p1[r] = (key0 + 16 <= q) ? s1[r] * cm : -1e30f;
      tmax = fmaxf(tmax, fmaxf(p0[r], p1[r]));
    }
    tmax = fmaxf(tmax, __shfl_xor(tmax, 16));
    tmax = fmaxf(tmax, __shfl_xor(tmax, 32));

    if (!__all(tmax <= mrun)) {            // exact defer: skip rescale when no-op
      float mnew = fmaxf(mrun, tmax);
      float al = __builtin_amdgcn_exp2f(mrun - mnew);
      mrun = mnew;
      lrun *= al;
#pragma unroll
      for (int t = 0; t < 4; ++t)
#pragma unroll
        for (int r = 0; r < 4; ++r) acc[t][r] *= al;
    }
    float sum = 0.0f;
#pragma unroll
    for (int r = 0; r < 4; ++r) {
      p0[r] = __builtin_amdgcn_exp2f(p0[r] - mrun);
      p1[r] = __builtin_amdgcn_exp2f(p1[r] - mrun);
      sum += p0[r] + p1[r];
    }
    sum += __shfl_xor(sum, 16);
    sum += __shfl_xor(sum, 32);
    lrun += sum;

    // repack P: [q=ln][key] via tiny LDS roundtrip -> B-fragment
    bf16x4 pb0 = { (__bf16)p0[0], (__bf16)p0[1], (__bf16)p0[2], (__bf16)p0[3] };
    bf16x4 pb1 = { (__bf16)p1[0], (__bf16)p1[1], (__bf16)p1[2], (__bf16)p1[3] };
    *(bf16x4*)(plds + (w * 16 + ln) * 56 + kg * 4) = pb0;
    *(bf16x4*)(plds + (w * 16 + ln) * 56 + 16 + kg * 4) = pb1;
    bf16x8 pf = *(const bf16x8*)(plds + (w * 16 + ln) * 56 + kg * 8);

    __builtin_amdgcn_s_setprio(1);
    acc[0] = __builtin_amdgcn_mfma_f32_16x16x32_bf16(vt0, pf, acc[0], 0, 0, 0);
    acc[1] = __builtin_amdgcn_mfma_f32_16x16x32_bf16(vt1, pf, acc[1], 0, 0, 0);
    acc[2] = __builtin_amdgcn_mfma_f32_16x16x32_bf16(vt2, pf, acc[2], 0, 0, 0);
    acc[3] = __builtin_amdgcn_mfma_f32_16x16x32_bf16(vt3, pf, acc[3], 0, 0, 0);
    __builtin_amdgcn_s_setprio(0);

    ka0 = na0; ka1 = na1; kc0 = nc0; kc1 = nc1;
  }

  __syncthreads();                          // all waves done with plds
  if (w > 0) {
    float* p = &smem[(w - 1) * 1280 + lane * 20];
    p[0] = mrun;
    p[1] = lrun;
#pragma unroll
    for (int t = 0; t < 4; ++t)
#pragma unroll
      for (int r = 0; r < 4; ++r) p[2 + t * 4 + r] = acc[t][r];
  }
  __syncthreads();
  if (w == 0) {
    float M = mrun;
#pragma unroll
    for (int ww = 0; ww < 3; ++ww) M = fmaxf(M, smem[ww * 1280 + lane * 20]);
    float wg0 = __builtin_amdgcn_exp2f(mrun - M);
    float l = lrun * wg0;
#pragma unroll
    for (int t = 0; t < 4; ++t)
#pragma unroll
      for (int r = 0; r < 4; ++r) acc[t][r] *= wg0;
#pragma unroll
    for (int ww = 0; ww < 3; ++ww) {
      const float* p = &smem[ww * 1280 + lane * 20];
      float wg = __builtin_amdgcn_exp2f(p[0] - M);
      l += wg * p[1];
#pragma unroll
      for (int t = 0; t < 4; ++t)
#pragma unroll
        for (int r = 0; r < 4; ++r) acc[t][r] += wg * p[2 + t * 4 + r];
    }
    const int b = bh >> 2, h = bh & 3;
    __bf16* yrow = yb + (b * SS + q) * CC + h * DD;
    float inv = 1.0f / l;
#pragma unroll
    for (int t = 0; t < 4; ++t) {
      bf16x4 o = { (__bf16)(acc[t][0] * inv), (__bf16)(acc[t][1] * inv),
                   (__bf16)(acc[t][2] * inv), (__bf16)(acc[t][3] * inv) };
      *(bf16x4*)(yrow + t * 16 + kg * 4) = o;
    }
  }
}

// ---------------- Proj GEMM: out = y @ W_proj^T (fp32 out) ------------------
__global__ __launch_bounds__(256) void proj_gemm(const __bf16* __restrict__ yb,
                                                 const __bf16* __restrict__ wpb,
                                                 float* __restrict__ out) {
  const int lane = threadIdx.x & 63;
  const int ln = lane & 15, kg = lane >> 4;
  const int w = threadIdx.x >> 6;
  const int otile = blockIdx.x & 3;
  const int r0 = (blockIdx.x >> 2) * 256 + w * 64;
  const int o0 = otile * 64;

  f32x4 acc[4][4] = {};
  for (int c0 = 0; c0 < CC; c0 += 32) {
    bf16x8 a[4], wv[4];
#pragma unroll
    for (int i = 0; i < 4; ++i)
      a[i] = *(const bf16x8*)(yb + (r0 + i * 16 + ln) * CC + c0 + kg * 8);
#pragma unroll
    for (int t = 0; t < 4; ++t)
      wv[t] = *(const bf16x8*)(wpb + (o0 + t * 16 + ln) * CC + c0 + kg * 8);
#pragma unroll
    for (int i = 0; i < 4; ++i)
#pragma unroll
      for (int t = 0; t < 4; ++t)
        acc[i][t] = __builtin_amdgcn_mfma_f32_16x16x32_bf16(a[i], wv[t], acc[i][t], 0, 0, 0);
  }
#pragma unroll
  for (int i = 0; i < 4; ++i)
#pragma unroll
    for (int t = 0; t < 4; ++t) {
      int o = o0 + t * 16 + ln;
#pragma unroll
      for (int r = 0; r < 4; ++r) {
        int rout = r0 + i * 16 + kg * 4 + r;
        out[rout * 256 + o] = acc[i][t][r];
      }
    }
}

extern "C" void kernel_launch(void* const* d_in, const int* in_sizes, int n_in,
                              void* d_out, int out_size, void* d_ws, size_t ws_size,
                              hipStream_t stream) {
  const float* x = (const float*)d_in[0];
  const float* Wa = (const float*)d_in[1];
  const float* Wp = (const float*)d_in[2];

  char* ws = (char*)d_ws;
  __bf16* xb  = (__bf16*)(ws);                    // 8 MiB  [B*S][C]
  __bf16* qb  = (__bf16*)(ws + 8388608);          // 8 MiB  [BH][S][D]
  __bf16* kb  = (__bf16*)(ws + 16777216);         // 8 MiB  [BH][S][D]
  __bf16* vtb = (__bf16*)(ws + 25165824);         // 8 MiB  [BH][D][S]
  __bf16* yb  = (__bf16*)(ws + 33554432);         // 8 MiB  [B,S,C]
  __bf16* wab = (__bf16*)(ws + 41943040);         // 384 KiB [768][256]
  __bf16* wpb = (__bf16*)(ws + 42336256);         // 128 KiB [256][256]

  cvt_kernel<<<(4194304 / 4 + 255) / 256, 256, 0, stream>>>(x, xb, 4194304 / 4);
  cvt_kernel<<<(196608 / 4 + 255) / 256, 256, 0, stream>>>(Wa, wab, 196608 / 4);
  cvt_kernel<<<(65536 / 4 + 255) / 256, 256, 0, stream>>>(Wp, wpb, 65536 / 4);

  qkv_gemm<<<768, 256, 0, stream>>>(xb, wab, qb, kb, vtb);
  attn_kernel<<<4096, 256, 0, stream>>>(qb, kb, vtb, yb);
  proj_gemm<<<256, 256, 0, stream>>>(yb, wpb, (float*)d_out);
}

// Round 4
// 127.749 us; speedup vs baseline: 2.5519x; 1.5609x over previous
//
#include <hip/hip_runtime.h>
#include <stdint.h>

// Causal self-attention: x[8,2048,256] fp32, W_attn[768,256], W_proj[256,256]
// cvt->bf16, QKV GEMM (K pre-scaled by 1/sqrt(D)*log2e, V transposed),
// flash attn: 32x32x16 MFMA, swapped QK, in-register softmax + cvt_pk/permlane
// P-repack (no LDS), proj GEMM.

#define BB 8
#define SS 2048
#define CC 256
#define HH 4
#define DD 64

typedef __attribute__((ext_vector_type(8))) __bf16 bf16x8;
typedef __attribute__((ext_vector_type(4))) __bf16 bf16x4;
typedef __attribute__((ext_vector_type(4))) float f32x4;
typedef __attribute__((ext_vector_type(16))) float f32x16;

#define CM 0.18033688011112042f   // (1/sqrt(64)) * log2(e), folded into K

static __device__ __forceinline__ uint32_t cvtpk(float lo, float hi) {
  uint32_t r;
  asm("v_cvt_pk_bf16_f32 %0, %1, %2" : "=v"(r) : "v"(lo), "v"(hi));
  return r;
}
static __device__ __forceinline__ void pl32swap(uint32_t& a, uint32_t& b) {
  asm("v_permlane32_swap_b32 %0, %1" : "+v"(a), "+v"(b));
}
union PU { uint32_t u[4]; bf16x8 v; };

// ---------------- fp32 -> bf16 convert ----------------
__global__ __launch_bounds__(256) void cvt_kernel(const float* __restrict__ in,
                                                  __bf16* __restrict__ out, int n4) {
  int i = blockIdx.x * blockDim.x + threadIdx.x;
  if (i >= n4) return;
  float4 v = ((const float4*)in)[i];
  bf16x4 o = { (__bf16)v.x, (__bf16)v.y, (__bf16)v.z, (__bf16)v.w };
  *(bf16x4*)(out + 4 * i) = o;
}

// ---------------- QKV GEMM: qkv = x @ W_attn^T ----------------
__global__ __launch_bounds__(256) void qkv_gemm(const __bf16* __restrict__ xb,
                                                const __bf16* __restrict__ wb,
                                                __bf16* __restrict__ qb,
                                                __bf16* __restrict__ kb,
                                                __bf16* __restrict__ vtb) {
  const int lane = threadIdx.x & 63;
  const int ln = lane & 15, kg = lane >> 4;
  const int w = threadIdx.x >> 6;
  const int otile = blockIdx.x % 12;
  const int r0 = (blockIdx.x / 12) * 256 + w * 64;
  const int o0 = otile * 64;

  f32x4 acc[4][4] = {};
  for (int c0 = 0; c0 < CC; c0 += 32) {
    bf16x8 a[4], wv[4];
#pragma unroll
    for (int i = 0; i < 4; ++i)
      a[i] = *(const bf16x8*)(xb + (r0 + i * 16 + ln) * CC + c0 + kg * 8);
#pragma unroll
    for (int t = 0; t < 4; ++t)
      wv[t] = *(const bf16x8*)(wb + (o0 + t * 16 + ln) * CC + c0 + kg * 8);
#pragma unroll
    for (int i = 0; i < 4; ++i)
#pragma unroll
      for (int t = 0; t < 4; ++t)
        acc[i][t] = __builtin_amdgcn_mfma_f32_16x16x32_bf16(a[i], wv[t], acc[i][t], 0, 0, 0);
  }
#pragma unroll
  for (int i = 0; i < 4; ++i)
#pragma unroll
    for (int t = 0; t < 4; ++t) {
      int o = o0 + t * 16 + ln;
      int sel = o >> 8;         // 0=q 1=k 2=v
      int oo = o & 255;
      int h = oo >> 6, d = oo & 63;
#pragma unroll
      for (int r = 0; r < 4; ++r) {
        int rout = r0 + i * 16 + kg * 4 + r;
        int b = rout >> 11, s = rout & 2047;
        if (sel == 0)      qb[((b * HH + h) * SS + s) * DD + d] = (__bf16)acc[i][t][r];
        else if (sel == 1) kb[((b * HH + h) * SS + s) * DD + d] = (__bf16)(acc[i][t][r] * CM);
        else               vtb[((b * HH + h) * DD + d) * SS + s] = (__bf16)acc[i][t][r];
      }
    }
}

// ---------------- Flash attention: 32x32 swapped-QK, in-register softmax ----
// 512 blocks x 4 waves. Wave owns 32 q-rows (one chunk). Blocks 0..255 take
// chunks 0..31 per bh; blocks 256..511 take 63-c (SIMD-pair load balance).
__global__ __launch_bounds__(256, 2) void attn_kernel(const __bf16* __restrict__ qb,
                                                      const __bf16* __restrict__ kb,
                                                      const __bf16* __restrict__ vtb,
                                                      __bf16* __restrict__ yb) {
  const int lane = threadIdx.x & 63;
  const int l31 = lane & 31;
  const int hi = lane >> 5;
  const int w = threadIdx.x >> 6;

  const int bid = blockIdx.x;
  const int half = bid >> 8;
  const int bb = bid & 255;
  const int xs = bb & 7;                 // XCD slot
  const int jj = bb >> 3;                // 0..31
  const int bh = xs + 8 * (jj & 3);      // 4 bh per XCD
  const int pg = jj >> 2;                // 0..7
  const int c0 = pg * 4 + w;             // 0..31
  const int c = half ? (63 - c0) : c0;   // 32-row chunk id
  const int q0w = c * 32;
  const int q = q0w + l31;

  const __bf16* Q = qb + bh * SS * DD;
  const __bf16* K = kb + bh * SS * DD;
  const __bf16* VT = vtb + bh * DD * SS;

  // Q fragments (B-operand): lane holds Q[q][hi*8 + j + 16s]
  bf16x8 qf[4];
  {
    const __bf16* Qp = Q + q * DD + hi * 8;
#pragma unroll
    for (int s = 0; s < 4; ++s) qf[s] = *(const bf16x8*)(Qp + s * 16);
  }

  f32x16 acc0 = {}, acc1 = {};
  float mrun = -1e30f, lrun = 0.0f;
  const int ntot = (q0w + 95) >> 6;      // 64-key tiles (last one = diagonal)
  const int qrel = l31 + 32 * (c & 1);   // q - kbase for the boundary tile

  // K fragments for tile 0 (A-operand rows = keys)
  bf16x8 ka[2][4];
  {
    const __bf16* Kp = K + l31 * DD + hi * 8;
#pragma unroll
    for (int s = 0; s < 4; ++s) {
      ka[0][s] = *(const bf16x8*)(Kp + s * 16);
      ka[1][s] = *(const bf16x8*)(Kp + 32 * DD + s * 16);
    }
  }

  for (int kt = 0; kt < ntot; ++kt) {
    const int kbase = kt * 64;
    // V loads (A-operand: rows = d); needed after softmax
    bf16x8 vf0[4], vf1[4];
    {
      const __bf16* Vp = VT + l31 * SS + kbase + hi * 8;
#pragma unroll
      for (int s = 0; s < 4; ++s) {
        vf0[s] = *(const bf16x8*)(Vp + s * 16);
        vf1[s] = *(const bf16x8*)(Vp + 32 * SS + s * 16);
      }
    }

    // QK^T (swapped): s0 = keys kbase..+31, s1 = +32..63; cols = q
    f32x16 s0 = {}, s1 = {};
    __builtin_amdgcn_s_setprio(1);
#pragma unroll
    for (int s = 0; s < 4; ++s) s0 = __builtin_amdgcn_mfma_f32_32x32x16_bf16(ka[0][s], qf[s], s0, 0, 0, 0);
#pragma unroll
    for (int s = 0; s < 4; ++s) s1 = __builtin_amdgcn_mfma_f32_32x32x16_bf16(ka[1][s], qf[s], s1, 0, 0, 0);
    __builtin_amdgcn_s_setprio(0);

    // prefetch next K tile
    {
      const int pb = (kt + 1 < ntot) ? (kbase + 64) : kbase;
      const __bf16* Kn = K + (pb + l31) * DD + hi * 8;
#pragma unroll
      for (int s = 0; s < 4; ++s) {
        ka[0][s] = *(const bf16x8*)(Kn + s * 16);
        ka[1][s] = *(const bf16x8*)(Kn + 32 * DD + s * 16);
      }
    }

    float p[32];
#pragma unroll
    for (int r = 0; r < 16; ++r) { p[r] = s0[r]; p[16 + r] = s1[r]; }
    if (kt == ntot - 1) {                 // diagonal tile: per-lane causal mask
#pragma unroll
      for (int r = 0; r < 16; ++r) {
        int crow = (r & 3) + 8 * (r >> 2) + 4 * hi;
        p[r]      = (crow      <= qrel) ? p[r]      : -1e30f;
        p[16 + r] = (crow + 32 <= qrel) ? p[16 + r] : -1e30f;
      }
    }

    // row max (tree) + cross-half
    float mx[16];
#pragma unroll
    for (int r = 0; r < 16; ++r) mx[r] = fmaxf(p[r], p[16 + r]);
#pragma unroll
    for (int st = 8; st > 0; st >>= 1)
#pragma unroll
      for (int r = 0; r < 8; ++r) if (r < st) mx[r] = fmaxf(mx[r], mx[r + st]);
    float tmax = fmaxf(mx[0], __shfl_xor(mx[0], 32));

    if (!__all(tmax <= mrun)) {           // exact defer: rescale only on new max
      float mnew = fmaxf(mrun, tmax);
      float al = __builtin_amdgcn_exp2f(mrun - mnew);
      mrun = mnew;
      lrun *= al;
      acc0 *= al;
      acc1 *= al;
    }
#pragma unroll
    for (int r = 0; r < 32; ++r) p[r] = __builtin_amdgcn_exp2f(p[r] - mrun);

    // row sum (tree) + cross-half
    float sm[16];
#pragma unroll
    for (int r = 0; r < 16; ++r) sm[r] = p[r] + p[16 + r];
#pragma unroll
    for (int st = 8; st > 0; st >>= 1)
#pragma unroll
      for (int r = 0; r < 8; ++r) if (r < st) sm[r] += sm[r + st];
    lrun += sm[0] + __shfl_xor(sm[0], 32);

    // repack P -> B-fragments (keys ascending per 16): cvt_pk + permlane32_swap
    bf16x8 pf[4];
#pragma unroll
    for (int g = 0; g < 4; ++g) {
      const int o = (g >> 1) * 16 + (g & 1) * 8;   // base index into p[]
      uint32_t a = cvtpk(p[o + 0], p[o + 1]);
      uint32_t b = cvtpk(p[o + 4], p[o + 5]);
      uint32_t c2 = cvtpk(p[o + 2], p[o + 3]);
      uint32_t d2 = cvtpk(p[o + 6], p[o + 7]);
      pl32swap(a, b);
      pl32swap(c2, d2);
      PU u; u.u[0] = a; u.u[1] = c2; u.u[2] = b; u.u[3] = d2;
      pf[g] = u.v;
    }

    // PV: acc[dg] += V^T[dg] . P
    __builtin_amdgcn_s_setprio(1);
#pragma unroll
    for (int g = 0; g < 4; ++g) acc0 = __builtin_amdgcn_mfma_f32_32x32x16_bf16(vf0[g], pf[g], acc0, 0, 0, 0);
#pragma unroll
    for (int g = 0; g < 4; ++g) acc1 = __builtin_amdgcn_mfma_f32_32x32x16_bf16(vf1[g], pf[g], acc1, 0, 0, 0);
    __builtin_amdgcn_s_setprio(0);
  }

  // epilogue: y[q][d] = acc^T / l ; write [B,S,C] with head offset
  const int b = bh >> 2, h = bh & 3;
  __bf16* yrow = yb + (b * SS + q) * CC + h * DD;
  float inv = __builtin_amdgcn_rcpf(lrun);
#pragma unroll
  for (int g = 0; g < 4; ++g) {
    {
      uint32_t w0 = cvtpk(acc0[g * 4 + 0] * inv, acc0[g * 4 + 1] * inv);
      uint32_t w1 = cvtpk(acc0[g * 4 + 2] * inv, acc0[g * 4 + 3] * inv);
      uint2 st = { w0, w1 };
      *(uint2*)(yrow + g * 8 + hi * 4) = st;
    }
    {
      uint32_t w0 = cvtpk(acc1[g * 4 + 0] * inv, acc1[g * 4 + 1] * inv);
      uint32_t w1 = cvtpk(acc1[g * 4 + 2] * inv, acc1[g * 4 + 3] * inv);
      uint2 st = { w0, w1 };
      *(uint2*)(yrow + 32 + g * 8 + hi * 4) = st;
    }
  }
}

// ---------------- Proj GEMM: out = y @ W_proj^T (fp32 out) ------------------
__global__ __launch_bounds__(256) void proj_gemm(const __bf16* __restrict__ yb,
                                                 const __bf16* __restrict__ wpb,
                                                 float* __restrict__ out) {
  const int lane = threadIdx.x & 63;
  const int ln = lane & 15, kg = lane >> 4;
  const int w = threadIdx.x >> 6;
  const int otile = blockIdx.x & 3;
  const int r0 = (blockIdx.x >> 2) * 256 + w * 64;
  const int o0 = otile * 64;

  f32x4 acc[4][4] = {};
  for (int c0 = 0; c0 < CC; c0 += 32) {
    bf16x8 a[4], wv[4];
#pragma unroll
    for (int i = 0; i < 4; ++i)
      a[i] = *(const bf16x8*)(yb + (r0 + i * 16 + ln) * CC + c0 + kg * 8);
#pragma unroll
    for (int t = 0; t < 4; ++t)
      wv[t] = *(const bf16x8*)(wpb + (o0 + t * 16 + ln) * CC + c0 + kg * 8);
#pragma unroll
    for (int i = 0; i < 4; ++i)
#pragma unroll
      for (int t = 0; t < 4; ++t)
        acc[i][t] = __builtin_amdgcn_mfma_f32_16x16x32_bf16(a[i], wv[t], acc[i][t], 0, 0, 0);
  }
#pragma unroll
  for (int i = 0; i < 4; ++i)
#pragma unroll
    for (int t = 0; t < 4; ++t) {
      int o = o0 + t * 16 + ln;
#pragma unroll
      for (int r = 0; r < 4; ++r) {
        int rout = r0 + i * 16 + kg * 4 + r;
        out[rout * 256 + o] = acc[i][t][r];
      }
    }
}

extern "C" void kernel_launch(void* const* d_in, const int* in_sizes, int n_in,
                              void* d_out, int out_size, void* d_ws, size_t ws_size,
                              hipStream_t stream) {
  const float* x = (const float*)d_in[0];
  const float* Wa = (const float*)d_in[1];
  const float* Wp = (const float*)d_in[2];

  char* ws = (char*)d_ws;
  __bf16* xb  = (__bf16*)(ws);                    // 8 MiB  [B*S][C]
  __bf16* qb  = (__bf16*)(ws + 8388608);          // 8 MiB  [BH][S][D]
  __bf16* kb  = (__bf16*)(ws + 16777216);         // 8 MiB  [BH][S][D] (pre-scaled)
  __bf16* vtb = (__bf16*)(ws + 25165824);         // 8 MiB  [BH][D][S]
  __bf16* yb  = (__bf16*)(ws + 33554432);         // 8 MiB  [B,S,C]
  __bf16* wab = (__bf16*)(ws + 41943040);         // 384 KiB [768][256]
  __bf16* wpb = (__bf16*)(ws + 42336256);         // 128 KiB [256][256]

  cvt_kernel<<<(4194304 / 4 + 255) / 256, 256, 0, stream>>>(x, xb, 4194304 / 4);
  cvt_kernel<<<(196608 / 4 + 255) / 256, 256, 0, stream>>>(Wa, wab, 196608 / 4);
  cvt_kernel<<<(65536 / 4 + 255) / 256, 256, 0, stream>>>(Wp, wpb, 65536 / 4);

  qkv_gemm<<<768, 256, 0, stream>>>(xb, wab, qb, kb, vtb);
  attn_kernel<<<512, 256, 0, stream>>>(qb, kb, vtb, yb);
  proj_gemm<<<256, 256, 0, stream>>>(yb, wpb, (float*)d_out);
}